// Round 9
// baseline (47.098 us; speedup 1.0000x reference)
//
#include <hip/hip_runtime.h>
#include <math.h>

#define NN 1024
#define DD 64
#define HH 256
#define TEMP_INV 10.0f

typedef float v2f __attribute__((ext_vector_type(2)));

// ws layout (floats):
//   x2T [HH][NN] : xp + b1, k-major (col j contiguous per k)   1 MB
//   y2  [NN][HH] : yp, row-major (k contiguous per row)        1 MB
//   pmax [16][NN], psum [16][NN], pos [NN]

__global__ __launch_bounds__(256)
void k1_proj(const float* __restrict__ x, const float* __restrict__ y,
             const float* __restrict__ W1, const float* __restrict__ b1,
             float* __restrict__ x2T, float* __restrict__ y2)
{
    const int tid = threadIdx.x;        // h index 0..255
    const int i0 = blockIdx.x * 2;      // 2 rows per block -> 512 blocks
    float ax0 = 0.f, ax1 = 0.f, ay0 = 0.f, ay1 = 0.f;
    #pragma unroll 8
    for (int kk = 0; kk < DD; ++kk) {
        const float wx = W1[kk * HH + tid];
        const float wy = W1[(DD + kk) * HH + tid];
        ax0 = fmaf(x[i0 * DD + kk],       wx, ax0);
        ax1 = fmaf(x[(i0 + 1) * DD + kk], wx, ax1);
        ay0 = fmaf(y[i0 * DD + kk],       wy, ay0);
        ay1 = fmaf(y[(i0 + 1) * DD + kk], wy, ay1);
    }
    const float b1t = b1[tid];
    *(float2*)&x2T[tid * NN + i0] = make_float2(ax0 + b1t, ax1 + b1t);
    y2[i0 * HH + tid]       = ay0;      // coalesced over tid
    y2[(i0 + 1) * HH + tid] = ay1;
}

// 32x64 tile per block, full K=256. NO LDS, NO barriers. Per-thread 4 rows x
// 2 packed cols (v2f accumulators -> v_pk_fma_f32). y: broadcast float4 from
// global (L1-hot); x: coalesced float2; w2: uniform scalar load.
__global__ __launch_bounds__(256)
void k2_scores(const float* __restrict__ x2T, const float* __restrict__ y2,
               const float* __restrict__ w2, const float* __restrict__ b2,
               float* __restrict__ pmax, float* __restrict__ psum,
               float* __restrict__ pos)
{
    const int t  = threadIdx.x;
    const int bj = blockIdx.x;          // 0..15 -> 64 cols
    const int bi = blockIdx.y;          // 0..31 -> 32 rows
    const int j0 = bj * 64;
    const int rbase = bi * 32 + (t >> 5) * 4;
    const int cc = t & 31;

    const float* yb = y2 + (size_t)rbase * HH;
    const float* xb = x2T + j0 + cc * 2;

    v2f a0 = {0.f, 0.f}, a1 = {0.f, 0.f}, a2 = {0.f, 0.f}, a3 = {0.f, 0.f};
    const v2f zero = {0.f, 0.f};

    #pragma unroll 2
    for (int g = 0; g < HH / 4; ++g) {
        const int kb = g * 4;
        const float4 yr0 = *(const float4*)&yb[kb];
        const float4 yr1 = *(const float4*)&yb[HH + kb];
        const float4 yr2 = *(const float4*)&yb[2 * HH + kb];
        const float4 yr3 = *(const float4*)&yb[3 * HH + kb];
        const v2f xv0 = *(const v2f*)&xb[(size_t)(kb + 0) * NN];
        const v2f xv1 = *(const v2f*)&xb[(size_t)(kb + 1) * NN];
        const v2f xv2 = *(const v2f*)&xb[(size_t)(kb + 2) * NN];
        const v2f xv3 = *(const v2f*)&xb[(size_t)(kb + 3) * NN];
#define STEP(XV, Y0, Y1, Y2, Y3, WK)                                          \
        {                                                                     \
            const float wk = (WK);                                            \
            const v2f wv = {wk, wk};                                          \
            v2f z;                                                            \
            z = XV + (v2f){(Y0), (Y0)};                                       \
            z = __builtin_elementwise_max(z, zero);                           \
            a0 = z * wv + a0;                                                 \
            z = XV + (v2f){(Y1), (Y1)};                                       \
            z = __builtin_elementwise_max(z, zero);                           \
            a1 = z * wv + a1;                                                 \
            z = XV + (v2f){(Y2), (Y2)};                                       \
            z = __builtin_elementwise_max(z, zero);                           \
            a2 = z * wv + a2;                                                 \
            z = XV + (v2f){(Y3), (Y3)};                                       \
            z = __builtin_elementwise_max(z, zero);                           \
            a3 = z * wv + a3;                                                 \
        }
        STEP(xv0, yr0.x, yr1.x, yr2.x, yr3.x, w2[kb + 0])
        STEP(xv1, yr0.y, yr1.y, yr2.y, yr3.y, w2[kb + 1])
        STEP(xv2, yr0.z, yr1.z, yr2.z, yr3.z, w2[kb + 2])
        STEP(xv3, yr0.w, yr1.w, yr2.w, yr3.w, w2[kb + 3])
#undef STEP
    }

    // epilogue: scores, diagonal -> pos, per-row partial LSE over 64 cols
    const float bb = b2[0];
    const v2f bbv = {bb, bb};
    v2f sc[4];
    sc[0] = (a0 + bbv) * TEMP_INV;
    sc[1] = (a1 + bbv) * TEMP_INV;
    sc[2] = (a2 + bbv) * TEMP_INV;
    sc[3] = (a3 + bbv) * TEMP_INV;

    const int col0 = j0 + cc * 2;
    #pragma unroll
    for (int p = 0; p < 4; ++p) {
        const int row = rbase + p;
        if (row == col0)     pos[row] = sc[p].x;
        if (row == col0 + 1) pos[row] = sc[p].y;
    }

    float m[4], e[4];
    #pragma unroll
    for (int p = 0; p < 4; ++p) {
        m[p] = fmaxf(sc[p].x, sc[p].y);
        e[p] = __expf(sc[p].x - m[p]) + __expf(sc[p].y - m[p]);
    }
    #pragma unroll
    for (int mk = 16; mk >= 1; mk >>= 1) {
        #pragma unroll
        for (int p = 0; p < 4; ++p) {
            const float mo = __shfl_xor(m[p], mk);
            const float eo = __shfl_xor(e[p], mk);
            const float mn = fmaxf(m[p], mo);
            e[p] = e[p] * __expf(m[p] - mn) + eo * __expf(mo - mn);
            m[p] = mn;
        }
    }
    if (cc == 0) {
        #pragma unroll
        for (int p = 0; p < 4; ++p) {
            pmax[bj * NN + rbase + p] = m[p];
            psum[bj * NN + rbase + p] = e[p];
        }
    }
}

// Single block, 1024 threads: one row per thread. Merge 16 j-chunk partials,
// add pos, block-reduce, write the scalar.
__global__ __launch_bounds__(1024)
void k3_final(const float* __restrict__ pmax, const float* __restrict__ psum,
              const float* __restrict__ pos, float* __restrict__ out)
{
    __shared__ float2 red[1024];
    const int tid = threadIdx.x;      // row
    float M = pmax[tid], E = psum[tid];
    #pragma unroll
    for (int jc = 1; jc < 16; ++jc) {
        const float Mo = pmax[jc * NN + tid];
        const float Eo = psum[jc * NN + tid];
        const float Mn = fmaxf(M, Mo);
        E = E * __expf(M - Mn) + Eo * __expf(Mo - Mn);
        M = Mn;
    }
    red[tid] = make_float2(M + logf(E), pos[tid]);
    __syncthreads();
    for (int s = 512; s > 0; s >>= 1) {
        if (tid < s) {
            const float2 o = red[tid + s];
            float2 m2 = red[tid];
            m2.x += o.x; m2.y += o.y;
            red[tid] = m2;
        }
        __syncthreads();
    }
    if (tid == 0)
        out[0] = red[0].x / (float)NN - logf((float)NN) - red[0].y / (float)NN;
}

extern "C" void kernel_launch(void* const* d_in, const int* in_sizes, int n_in,
                              void* d_out, int out_size, void* d_ws, size_t ws_size,
                              hipStream_t stream)
{
    const float* x  = (const float*)d_in[0];
    const float* y  = (const float*)d_in[1];
    const float* W1 = (const float*)d_in[2];
    const float* b1 = (const float*)d_in[3];
    const float* w2 = (const float*)d_in[4];
    const float* b2 = (const float*)d_in[5];
    float* out = (float*)d_out;

    float* ws   = (float*)d_ws;
    float* x2T  = ws;                 // 256*1024
    float* y2   = x2T + HH * NN;      // 1024*256
    float* pmax = y2 + NN * HH;       // 16*1024
    float* psum = pmax + 16 * NN;     // 16*1024
    float* pos  = psum + 16 * NN;     // 1024

    hipLaunchKernelGGL(k1_proj, dim3(NN / 2), dim3(256), 0, stream,
                       x, y, W1, b1, x2T, y2);
    hipLaunchKernelGGL(k2_scores, dim3(16, 32), dim3(256), 0, stream,
                       x2T, y2, w2, b2, pmax, psum, pos);
    hipLaunchKernelGGL(k3_final, dim3(1), dim3(1024), 0, stream,
                       pmax, psum, pos, out);
}